// Round 14
// baseline (260.750 us; speedup 1.0000x reference)
//
#include <hip/hip_runtime.h>
#include <math.h>

#define NN 12800
#define NE 204800
#define LL 24
#define HH 128
#define BB 64
#define RR 8
#define VAx 20
#define KC 1152  // R*H + H
#define CHK 8    // node chunks per batch for aggS
#define PS 16    // counter padding (ints per 64B line)

typedef __attribute__((ext_vector_type(8))) short bf16x8;
typedef __attribute__((ext_vector_type(4))) float f32x4;

__device__ inline unsigned short f2bf(float f) {
  unsigned u = __float_as_uint(f);
  unsigned r = u + 0x7FFF + ((u >> 16) & 1);  // RNE
  return (unsigned short)(r >> 16);
}
__device__ inline float bf2f(unsigned short s) {
  return __uint_as_float(((unsigned)s) << 16);
}
__device__ inline unsigned packbf(float lo, float hi) {
  return (unsigned)f2bf(lo) | ((unsigned)f2bf(hi) << 16);
}

// ---------------- mega prep: weight transforms + embed + edge count + batch boundary ----------------
// deg must be zeroed (hipMemsetAsync) BEFORE this kernel.
__global__ void k_prep(const float* __restrict__ rgcnW, const float* __restrict__ rgcnRoot,
                       unsigned short* __restrict__ wcatT,
                       const float* __restrict__ linN_w, unsigned short* __restrict__ linN2bt,
                       const float* __restrict__ Wih, unsigned short* __restrict__ Wihbt,
                       const float* __restrict__ Whh, float* __restrict__ WhhT,
                       const float* __restrict__ linA_w, float* __restrict__ linAT,
                       const float* __restrict__ fin_w, float* __restrict__ finT,
                       unsigned short* __restrict__ linN1bt,
                       const int* __restrict__ nt, const float* __restrict__ embN,
                       unsigned int* __restrict__ x, int* __restrict__ deg,
                       const int* __restrict__ edst, const int* __restrict__ bs,
                       int* __restrict__ bptr) {
  int idx = blockIdx.x * 256 + threadIdx.x;
  if (idx < HH * KC) {  // wcatT[d][k]
    int d = idx / KC, k = idx - d * KC;
    float v = (k < 1024) ? rgcnW[(k >> 7) * (HH * HH) + (k & 127) * HH + d]
                         : rgcnRoot[(k - 1024) * HH + d];
    wcatT[idx] = f2bf(v);
    return;
  }
  idx -= HH * KC;
  if (idx < HH * HH) {  // linN2bt[d][k] = linN_w[d][128+k]
    int d = idx >> 7, k = idx & 127;
    linN2bt[idx] = f2bf(linN_w[d * 2 * HH + HH + k]);
    return;
  }
  idx -= HH * HH;
  if (idx < 3 * HH * HH) {  // Wihbt = bf16(Wih), already [384][128] B-layout
    Wihbt[idx] = f2bf(Wih[idx]);
    return;
  }
  idx -= 3 * HH * HH;
  if (idx < 3 * HH * HH) {  // WhhT (fp32 transpose for GRU)
    int r = idx / HH, c = idx - r * HH;
    WhhT[c * 384 + r] = Whh[r * HH + c];
    return;
  }
  idx -= 3 * HH * HH;
  if (idx < HH * HH) {  // linAT
    int r = idx >> 7, c = idx & 127;
    linAT[c * HH + r] = linA_w[r * HH + c];
    return;
  }
  idx -= HH * HH;
  if (idx < HH * HH) {  // finT
    int r = idx >> 7, c = idx & 127;
    finT[c * HH + r] = fin_w[r * HH + c];
    return;
  }
  idx -= HH * HH;
  if (idx < HH * HH) {  // linN1bt[o][k] = bf16(linN_w[o][k])
    int o = idx >> 7, k = idx & 127;
    linN1bt[idx] = f2bf(linN_w[o * 2 * HH + k]);
    return;
  }
  idx -= HH * HH;
  if (idx < NN * 64) {  // embed -> bf16 pairs
    int n = idx >> 6, p = idx & 63;
    const float* e = embN + (size_t)nt[n] * HH + p * 2;
    x[idx] = packbf(e[0], e[1]);
    return;
  }
  idx -= NN * 64;
  if (idx < NE) {  // edge-degree count (padded counters, pre-zeroed)
    atomicAdd(&deg[edst[idx] * PS], 1);
    return;
  }
  idx -= NE;
  if (idx < NN) {  // bs sorted -> batch boundary detection
    int b = bs[idx];
    if (idx == 0 || bs[idx - 1] != b) bptr[b] = idx;
    if (idx == NN - 1) bptr[BB] = NN;
  }
}
#define PREP_TOTAL (HH * KC + HH * HH + 3 * HH * HH + 3 * HH * HH + HH * HH + HH * HH + HH * HH + NN * 64 + NE + NN)

// single-block scan over padded deg -> compact indptr + padded cur
__global__ __launch_bounds__(1024) void k_scane(const int* __restrict__ deg,
                                                int* __restrict__ indptr,
                                                int* __restrict__ cur) {
  __shared__ int ws[16];
  int tid = threadIdx.x;
  const int per = (NN + 1023) >> 10;
  int i0 = tid * per;
  int s = 0;
  for (int k = 0; k < per; ++k) {
    int i = i0 + k;
    if (i < NN) s += deg[i * PS];
  }
  int lane = tid & 63, wv = tid >> 6;
  int incl = s;
#pragma unroll
  for (int off = 1; off < 64; off <<= 1) {
    int t = __shfl_up(incl, off);
    if (lane >= off) incl += t;
  }
  if (lane == 63) ws[wv] = incl;
  __syncthreads();
  if (tid < 16) {
    int v = ws[tid];
    int inc = v;
#pragma unroll
    for (int off = 1; off < 16; off <<= 1) {
      int t = __shfl_up(inc, off);
      if (tid >= off) inc += t;
    }
    ws[tid] = inc - v;  // exclusive
  }
  __syncthreads();
  int run = ws[wv] + incl - s;
  for (int k = 0; k < per; ++k) {
    int i = i0 + k;
    if (i < NN) {
      indptr[i] = run;
      cur[i * PS] = run;
      run += deg[i * PS];
      if (i == NN - 1) indptr[NN] = run;
    }
  }
}

__global__ void k_scattere(const int* __restrict__ esrc, const int* __restrict__ edst,
                           const int* __restrict__ erel, int* __restrict__ cur,
                           int* __restrict__ esort) {
  int i = blockIdx.x * 256 + threadIdx.x;
  if (i >= NE) return;
  int p = atomicAdd(&cur[edst[i] * PS], 1);
  esort[p] = esrc[i] | (erel[i] << 16);
}

// ---------------- RGCN aggregation: one wave per node, 8-deep gather pipeline ----------------
__global__ __launch_bounds__(256) void k_agg(const unsigned int* __restrict__ x,
                                             const int* __restrict__ indptr,
                                             const int* __restrict__ esort,
                                             unsigned int* __restrict__ A, int n0, int nc) {
  int wid = ((blockIdx.x * 256) + threadIdx.x) >> 6;
  int lane = threadIdx.x & 63;
  if (wid >= nc) return;
  int n = n0 + wid;
  float a0=0,a1=0,a2=0,a3=0,a4=0,a5=0,a6=0,a7=0;
  float b0=0,b1=0,b2=0,b3=0,b4=0,b5=0,b6=0,b7=0;
  int c0=0,c1=0,c2=0,c3=0,c4=0,c5=0,c6=0,c7=0;
  int e0 = indptr[n], e1 = indptr[n + 1];

#define ACCV(RV, VV)                                                              \
  {                                                                               \
    float v0_ = bf2f((unsigned short)((VV) & 0xFFFF));                            \
    float v1_ = bf2f((unsigned short)((VV) >> 16));                               \
    switch (RV) {                                                                 \
      case 0: a0 += v0_; b0 += v1_; c0++; break;                                  \
      case 1: a1 += v0_; b1 += v1_; c1++; break;                                  \
      case 2: a2 += v0_; b2 += v1_; c2++; break;                                  \
      case 3: a3 += v0_; b3 += v1_; c3++; break;                                  \
      case 4: a4 += v0_; b4 += v1_; c4++; break;                                  \
      case 5: a5 += v0_; b5 += v1_; c5++; break;                                  \
      case 6: a6 += v0_; b6 += v1_; c6++; break;                                  \
      default: a7 += v0_; b7 += v1_; c7++; break;                                 \
    }                                                                             \
  }

  int e = e0;
  for (; e + 8 <= e1; e += 8) {  // 8 independent gather chains in flight
    int pk0 = esort[e + 0], pk1 = esort[e + 1], pk2 = esort[e + 2], pk3 = esort[e + 3];
    int pk4 = esort[e + 4], pk5 = esort[e + 5], pk6 = esort[e + 6], pk7 = esort[e + 7];
    unsigned v0 = x[(size_t)(pk0 & 0xFFFF) * 64 + lane];
    unsigned v1 = x[(size_t)(pk1 & 0xFFFF) * 64 + lane];
    unsigned v2 = x[(size_t)(pk2 & 0xFFFF) * 64 + lane];
    unsigned v3 = x[(size_t)(pk3 & 0xFFFF) * 64 + lane];
    unsigned v4 = x[(size_t)(pk4 & 0xFFFF) * 64 + lane];
    unsigned v5 = x[(size_t)(pk5 & 0xFFFF) * 64 + lane];
    unsigned v6 = x[(size_t)(pk6 & 0xFFFF) * 64 + lane];
    unsigned v7 = x[(size_t)(pk7 & 0xFFFF) * 64 + lane];
    ACCV(pk0 >> 16, v0);
    ACCV(pk1 >> 16, v1);
    ACCV(pk2 >> 16, v2);
    ACCV(pk3 >> 16, v3);
    ACCV(pk4 >> 16, v4);
    ACCV(pk5 >> 16, v5);
    ACCV(pk6 >> 16, v6);
    ACCV(pk7 >> 16, v7);
  }
  for (; e + 4 <= e1; e += 4) {
    int pk0 = esort[e + 0], pk1 = esort[e + 1], pk2 = esort[e + 2], pk3 = esort[e + 3];
    unsigned v0 = x[(size_t)(pk0 & 0xFFFF) * 64 + lane];
    unsigned v1 = x[(size_t)(pk1 & 0xFFFF) * 64 + lane];
    unsigned v2 = x[(size_t)(pk2 & 0xFFFF) * 64 + lane];
    unsigned v3 = x[(size_t)(pk3 & 0xFFFF) * 64 + lane];
    ACCV(pk0 >> 16, v0);
    ACCV(pk1 >> 16, v1);
    ACCV(pk2 >> 16, v2);
    ACCV(pk3 >> 16, v3);
  }
  for (; e < e1; ++e) {
    int pk = esort[e];
    unsigned v = x[(size_t)(pk & 0xFFFF) * 64 + lane];
    ACCV(pk >> 16, v);
  }
#undef ACCV

  unsigned int* Ar = A + (size_t)wid * (KC / 2);
  float i0 = 1.0f / (float)(c0 > 0 ? c0 : 1);
  float i1 = 1.0f / (float)(c1 > 0 ? c1 : 1);
  float i2 = 1.0f / (float)(c2 > 0 ? c2 : 1);
  float i3 = 1.0f / (float)(c3 > 0 ? c3 : 1);
  float i4 = 1.0f / (float)(c4 > 0 ? c4 : 1);
  float i5 = 1.0f / (float)(c5 > 0 ? c5 : 1);
  float i6 = 1.0f / (float)(c6 > 0 ? c6 : 1);
  float i7 = 1.0f / (float)(c7 > 0 ? c7 : 1);
  Ar[0 * 64 + lane] = packbf(a0 * i0, b0 * i0);
  Ar[1 * 64 + lane] = packbf(a1 * i1, b1 * i1);
  Ar[2 * 64 + lane] = packbf(a2 * i2, b2 * i2);
  Ar[3 * 64 + lane] = packbf(a3 * i3, b3 * i3);
  Ar[4 * 64 + lane] = packbf(a4 * i4, b4 * i4);
  Ar[5 * 64 + lane] = packbf(a5 * i5, b5 * i5);
  Ar[6 * 64 + lane] = packbf(a6 * i6, b6 * i6);
  Ar[7 * 64 + lane] = packbf(a7 * i7, b7 * i7);
  Ar[512 + lane] = x[n * 64 + lane];  // root term
}

// ---------------- RGCN GEMM, 32-row tiles: C=A*BT^T, bias+relu+bf16 ----------------
__global__ __launch_bounds__(256) void k_mgemm_rg32(const unsigned short* __restrict__ Abf,
                                                    const unsigned short* __restrict__ BTbf,
                                                    const float* __restrict__ bias,
                                                    unsigned short* __restrict__ C) {
  __shared__ unsigned int ldsu[(4096 + 16384) / 4];
  char* ldsc = (char*)ldsu;
  int tid = threadIdx.x;
  int m0 = blockIdx.x * 32;
  int w = tid >> 6, l = tid & 63;
  int lrow = l & 15, lg = l >> 4;
  int rowg = w & 1, colg = w >> 1;
  f32x4 acc[4] = {};

  const char* Ab = (const char*)Abf;
  const char* Bb = (const char*)BTbf;
  for (int kt = 0; kt < KC / 64; ++kt) {
    int k0 = kt << 6;
    {  // A: 32 rows x 64 cols bf16 = 4KB
      int slot = tid;
      int row = slot >> 3;
      int colb = (slot & 7) << 4;
      size_t srcb = ((size_t)(m0 + row) * KC + k0) * 2 + (size_t)(colb ^ ((row & 7) << 4));
      __builtin_amdgcn_global_load_lds((const unsigned int*)(Ab + srcb),
                                       (unsigned int*)(ldsc + slot * 16), 16, 0, 0);
    }
#pragma unroll
    for (int i = 0; i < 4; ++i) {  // B: 128 rows x 64 cols = 16KB at +4096
      int slot = i * 256 + tid;
      int row = slot >> 3;
      int colb = (slot & 7) << 4;
      size_t srcb = ((size_t)row * KC + k0) * 2 + (size_t)(colb ^ ((row & 7) << 4));
      __builtin_amdgcn_global_load_lds((const unsigned int*)(Bb + srcb),
                                       (unsigned int*)(ldsc + 4096 + slot * 16), 16, 0, 0);
    }
    __syncthreads();
#pragma unroll
    for (int h = 0; h < 2; ++h) {
      int arow = rowg * 16 + lrow;
      bf16x8 af = *(const bf16x8*)(ldsc + arow * 128 +
                                   ((h * 64 + lg * 16) ^ ((arow & 7) << 4)));
#pragma unroll
      for (int c = 0; c < 4; ++c) {
        int brow = (colg * 4 + c) * 16 + lrow;
        bf16x8 bfr = *(const bf16x8*)(ldsc + 4096 + brow * 128 +
                                      ((h * 64 + lg * 16) ^ ((brow & 7) << 4)));
        acc[c] = __builtin_amdgcn_mfma_f32_16x16x32_bf16(af, bfr, acc[c], 0, 0, 0);
      }
    }
    __syncthreads();
  }
#pragma unroll
  for (int c = 0; c < 4; ++c) {
    int gn = (colg * 4 + c) * 16 + lrow;
    float bv = bias[gn];
#pragma unroll
    for (int r = 0; r < 4; ++r) {
      int gm = m0 + rowg * 16 + lg * 4 + r;
      float v = fmaxf(acc[c][r] + bv, 0.f);
      C[(size_t)gm * HH + gn] = f2bf(v);
    }
  }
}

// ---------------- merged gi + part2 GEMMs + heads (all depend only on aggS_red) ----------------
// blocks [0,72): gi = ig @ Wih^T + bih (N split 3x128). [72,272): part2. [272,400): heads.
__global__ __launch_bounds__(256) void k_gp_heads(const unsigned short* __restrict__ ig,
                                                  const unsigned short* __restrict__ Wihbt,
                                                  const float* __restrict__ bih,
                                                  float* __restrict__ gi,
                                                  const unsigned short* __restrict__ nodeEmb,
                                                  const unsigned short* __restrict__ linN2bt,
                                                  float* __restrict__ part2,
                                                  const float* __restrict__ hG,
                                                  const float* __restrict__ linAT,
                                                  const float* __restrict__ linA_b,
                                                  const float* __restrict__ linAf_w,
                                                  const float* __restrict__ linAf_b,
                                                  const float* __restrict__ finT,
                                                  const float* __restrict__ fin_b,
                                                  const float* __restrict__ finf_w,
                                                  const float* __restrict__ finf_b,
                                                  float* __restrict__ outA,
                                                  float* __restrict__ outF) {
  int tid = threadIdx.x;
  int bid = blockIdx.x;
  const int GIB = (BB * LL / 64) * 3;      // 72
  const int GEMMB = GIB + NN / 64;         // 272
  if (bid >= GEMMB) {  // ---- heads ----
    int hb = bid - GEMMB;
    int b = hb >> 1, which = hb & 1, j = tid;
    __shared__ float hsh[HH], t1[HH];
    if (j < HH) hsh[j] = hG[b * HH + j];
    __syncthreads();
    if (j < HH) {
      const float* Wt = which ? finT : linAT;
      const float* bb = which ? fin_b : linA_b;
      float s = bb[j];
      for (int k = 0; k < HH; ++k) s = fmaf(hsh[k], Wt[k * HH + j], s);
      t1[j] = fmaxf(s, 0.f);
    }
    __syncthreads();
    if (which == 0) {
      if (j < VAx) {
        float o = linAf_b[j];
        for (int k = 0; k < HH; ++k) o = fmaf(t1[k], linAf_w[j * HH + k], o);
        outA[b * VAx + j] = o;
      }
    } else if (j == 0) {
      float o = finf_b[0];
      for (int k = 0; k < HH; ++k) o = fmaf(t1[k], finf_w[k], o);
      outF[b] = 1.f / (1.f + expf(-o));
    }
    return;
  }
  // ---- GEMMs ----
  __shared__ unsigned int ldsu[(8192 + 16384) / 4];
  char* ldsc = (char*)ldsu;
  const unsigned short* Abf;
  const unsigned short* BTbf;
  const float* bias;
  float* Cf;
  int m0, ldc, withbias;
  if (bid < GIB) {
    int mb = bid / 3, nc = bid % 3;
    Abf = ig;
    BTbf = Wihbt + (size_t)(nc * 128) * HH;
    bias = bih + nc * 128;
    Cf = gi + nc * 128;
    m0 = mb * 64;
    ldc = 3 * HH;
    withbias = 1;
  } else {
    Abf = nodeEmb;
    BTbf = linN2bt;
    bias = nullptr;
    Cf = part2;
    m0 = (bid - GIB) * 64;
    ldc = HH;
    withbias = 0;
  }
  int w = tid >> 6, l = tid & 63;
  int lrow = l & 15, lg = l >> 4;
  f32x4 acc[8] = {};
  const char* Ab = (const char*)Abf;
  const char* Bb = (const char*)BTbf;
  for (int kt = 0; kt < 2; ++kt) {  // K = 128
    int k0 = kt << 6;
#pragma unroll
    for (int i = 0; i < 2; ++i) {
      int slot = i * 256 + tid;
      int row = slot >> 3;
      int colb = (slot & 7) << 4;
      size_t srcb = ((size_t)(m0 + row) * HH + k0) * 2 + (size_t)(colb ^ ((row & 7) << 4));
      __builtin_amdgcn_global_load_lds((const unsigned int*)(Ab + srcb),
                                       (unsigned int*)(ldsc + slot * 16), 16, 0, 0);
    }
#pragma unroll
    for (int i = 0; i < 4; ++i) {
      int slot = i * 256 + tid;
      int row = slot >> 3;
      int colb = (slot & 7) << 4;
      size_t srcb = ((size_t)row * HH + k0) * 2 + (size_t)(colb ^ ((row & 7) << 4));
      __builtin_amdgcn_global_load_lds((const unsigned int*)(Bb + srcb),
                                       (unsigned int*)(ldsc + 8192 + slot * 16), 16, 0, 0);
    }
    __syncthreads();
#pragma unroll
    for (int h = 0; h < 2; ++h) {
      int arow = w * 16 + lrow;
      bf16x8 af = *(const bf16x8*)(ldsc + arow * 128 +
                                   ((h * 64 + lg * 16) ^ ((arow & 7) << 4)));
#pragma unroll
      for (int c = 0; c < 8; ++c) {
        int brow = c * 16 + lrow;
        bf16x8 bfr = *(const bf16x8*)(ldsc + 8192 + brow * 128 +
                                      ((h * 64 + lg * 16) ^ ((brow & 7) << 4)));
        acc[c] = __builtin_amdgcn_mfma_f32_16x16x32_bf16(af, bfr, acc[c], 0, 0, 0);
      }
    }
    __syncthreads();
  }
#pragma unroll
  for (int c = 0; c < 8; ++c) {
    int gn = c * 16 + lrow;
    float bv = withbias ? bias[gn] : 0.f;
#pragma unroll
    for (int r = 0; r < 4; ++r) {
      int gm = m0 + w * 16 + lg * 4 + r;
      Cf[(size_t)gm * ldc + gn] = acc[c][r] + bv;
    }
  }
}

// ---------------- aggS partials: 512 blocks (64 batches x 8 chunks) ----------------
__global__ __launch_bounds__(256) void k_aggS_part(const float* __restrict__ seqin,
                                                   const unsigned short* __restrict__ x,
                                                   const int* __restrict__ bptr,
                                                   float* __restrict__ part) {
  int bc = blockIdx.x, b = bc >> 3, c = bc & 7;
  int h = threadIdx.x & 127, l0 = threadIdx.x >> 7;  // l0 in {0,1}
  int i0 = bptr[b], i1 = bptr[b + 1];
  int len = i1 - i0;
  int per = (len + CHK - 1) / CHK;
  int j0 = i0 + c * per;
  int j1 = j0 + per;
  if (j1 > i1) j1 = i1;
  float acc[12] = {};
  float esum = 0.f;
  for (int n = j0; n < j1; ++n) {  // bnodes == identity (bs sorted)
    float e = bf2f(x[n * HH + h]);
    esum += e;
    const float* srow = seqin + (size_t)n * LL;
#pragma unroll
    for (int t = 0; t < 12; ++t) acc[t] = fmaf(srow[l0 + 2 * t], e, acc[t]);
  }
  float* p = part + (size_t)bc * 25 * HH + h;
#pragma unroll
  for (int t = 0; t < 12; ++t) p[(l0 + 2 * t) * HH] = acc[t];
  if (l0 == 0) p[24 * HH] = esum;
}

// reduce partials; writes ig (bf16, with SOS at t=0) and hG (fp32)
__global__ void k_aggS_red(const float* __restrict__ part, const int* __restrict__ bptr,
                           const float* __restrict__ embA, const int* __restrict__ act,
                           unsigned short* __restrict__ ig, float* __restrict__ hG) {
  int idx = blockIdx.x * 256 + threadIdx.x;
  if (idx >= BB * 25 * HH) return;
  int h = idx & 127;
  int rem = idx >> 7;
  int l = rem % 25, b = rem / 25;
  if (l == 23) {  // agg[23] dropped by [:, :L]; reuse slot for ig[b][0] = SOS
    ig[((size_t)b * LL) * HH + h] = f2bf(embA[(size_t)act[b] * HH + h]);
    return;
  }
  float s = 0.f;
#pragma unroll
  for (int c = 0; c < CHK; ++c) s += part[(((size_t)(b * CHK + c)) * 25 + l) * HH + h];
  if (l == 24) {
    int len = bptr[b + 1] - bptr[b];
    hG[b * HH + h] = s / (float)len;
  } else {
    ig[((size_t)b * LL + l + 1) * HH + h] = f2bf(s);
  }
}

// ---------------- GRU + fused part1: 64 blocks x 384 threads ----------------
// Recurrence identical to the verified k_gru; seq values (bf16-rounded, same as the
// old seqb path) are kept in LDS; epilogue computes part1[b] = seq @ linN1^T with
// bf16 products + fp32 accumulation (same products as the old MFMA path).
__global__ __launch_bounds__(384) void k_gru(const float* __restrict__ gi,
                                             const float* __restrict__ WhhT,  // [128][384]
                                             const float* __restrict__ bhh,
                                             const float* __restrict__ hG,
                                             const unsigned short* __restrict__ linN1bt,
                                             float* __restrict__ part1) {
  int b = blockIdx.x, tid = threadIdx.x;
  int gate = tid >> 7, j = tid & 127;
  __shared__ float h[HH];
  __shared__ float sz[HH], sg[HH];
  __shared__ float seqf[LL][HH];  // bf16-rounded seq values, fp32 storage
  float w[HH];
#pragma unroll
  for (int k = 0; k < HH; ++k) w[k] = WhhT[k * 384 + tid];
  float bh = bhh[tid];
  if (tid < HH) h[tid] = hG[b * HH + tid];
  __syncthreads();
  const float* gib = gi + (size_t)b * LL * 384;
  for (int t = 0; t < LL; ++t) {
    float giv = gib[t * 384 + tid];
    float gin = (gate == 0) ? gib[t * 384 + 256 + j] : 0.f;  // wave-uniform branch
    float hj = h[j];
    float g0 = 0.f, g1 = 0.f, g2 = 0.f, g3 = 0.f;
    const float4* h4 = (const float4*)h;
#pragma unroll
    for (int k4 = 0; k4 < HH / 4; ++k4) {
      float4 hv = h4[k4];
      g0 = fmaf(w[4 * k4 + 0], hv.x, g0);
      g1 = fmaf(w[4 * k4 + 1], hv.y, g1);
      g2 = fmaf(w[4 * k4 + 2], hv.z, g2);
      g3 = fmaf(w[4 * k4 + 3], hv.w, g3);
    }
    float g = bh + ((g0 + g1) + (g2 + g3));
    float r = 0.f;
    if (gate == 0) {
      r = 1.f / (1.f + expf(-(giv + g)));
    } else if (gate == 1) {
      sz[j] = 1.f / (1.f + expf(-(giv + g)));
    } else {
      sg[j] = g;
    }
    __syncthreads();
    if (gate == 0) {
      float n = tanhf(gin + r * sg[j]);
      float z = sz[j];
      float hn = (1.f - z) * n + z * hj;
      h[j] = hn;
      seqf[t][j] = bf2f(f2bf(hn));  // bf16-rounded, matching old seqb path
    }
    __syncthreads();
  }
  // ---- fused part1: thread computes 8 of the 3072 (t,o) outputs ----
  float* p1 = part1 + (size_t)b * LL * HH;
#pragma unroll
  for (int s = 0; s < 8; ++s) {
    int p = s * 384 + tid;
    int t = p >> 7, o = p & 127;
    const unsigned* wrow = (const unsigned*)(linN1bt + (size_t)o * HH);
    const float* sr = seqf[t];
    float acc = 0.f;
#pragma unroll 16
    for (int k2 = 0; k2 < HH / 2; ++k2) {
      unsigned pk = wrow[k2];
      acc = fmaf(sr[2 * k2], bf2f((unsigned short)(pk & 0xFFFF)), acc);
      acc = fmaf(sr[2 * k2 + 1], bf2f((unsigned short)(pk >> 16)), acc);
    }
    p1[(size_t)t * HH + o] = acc;
  }
}

// ---------------- fused logits + segment softmax: one block per (b,l) ----------------
__global__ __launch_bounds__(256) void k_logsm(const float* __restrict__ part1,
                                               const float* __restrict__ part2,
                                               const float* __restrict__ linN_b,
                                               const float* __restrict__ linNf_w,
                                               const float* __restrict__ linNf_b,
                                               const int* __restrict__ bptr,
                                               float* __restrict__ outN) {
  int bl = blockIdx.x;
  int b = bl / LL, l = bl % LL;
  __shared__ float p1b[HH], wsh[HH], lg[256], red[8];
  int tid = threadIdx.x;
  int w = tid >> 6, lane = tid & 63;
  if (tid < HH) {
    p1b[tid] = part1[((size_t)b * LL + l) * HH + tid] + linN_b[tid];
    wsh[tid] = linNf_w[tid];
  }
  __syncthreads();
  int i0 = bptr[b], i1 = bptr[b + 1];
  int len = i1 - i0;  // 200 for this problem (<=256 assumed)
  float bf = linNf_b[0];
  for (int i = i0 + w; i < i1; i += 4) {
    const float* p2 = part2 + (size_t)i * HH;
    float v = fmaxf(p1b[lane] + p2[lane], 0.f) * wsh[lane] +
              fmaxf(p1b[64 + lane] + p2[64 + lane], 0.f) * wsh[64 + lane];
#pragma unroll
    for (int off = 32; off > 0; off >>= 1) v += __shfl_down(v, off);
    if (lane == 0) lg[i - i0] = v + bf;
  }
  __syncthreads();
  float m = (tid < len) ? lg[tid] : -1e30f;
#pragma unroll
  for (int off = 32; off > 0; off >>= 1) m = fmaxf(m, __shfl_xor(m, off));
  if (lane == 0) red[w] = m;
  __syncthreads();
  m = fmaxf(fmaxf(red[0], red[1]), fmaxf(red[2], red[3]));
  float e = (tid < len) ? expf(lg[tid] - m) : 0.f;
  float s = e;
#pragma unroll
  for (int off = 32; off > 0; off >>= 1) s += __shfl_xor(s, off);
  if (lane == 0) red[4 + w] = s;
  __syncthreads();
  s = (red[4] + red[5]) + (red[6] + red[7]);
  if (tid < len) outN[(size_t)(i0 + tid) * LL + l] = e / s;
}

// ---------------- host ----------------
extern "C" void kernel_launch(void* const* d_in, const int* in_sizes, int n_in,
                              void* d_out, int out_size, void* d_ws, size_t ws_size,
                              hipStream_t stream) {
  const int* nodeTypes = (const int*)d_in[0];
  const int* esrc = (const int*)d_in[1];
  const int* edst = esrc + NE;
  const int* erel = (const int*)d_in[2];
  const int* bs = (const int*)d_in[3];
  const float* seqin = (const float*)d_in[4];
  const int* actin = (const int*)d_in[7];
  const float* embN = (const float*)d_in[8];
  const float* embA = (const float*)d_in[9];
  const float* rgcnW = (const float*)d_in[10];
  const float* rgcnRoot = (const float*)d_in[11];
  const float* rgcnB = (const float*)d_in[12];
  const float* Wih = (const float*)d_in[13];
  const float* Whh = (const float*)d_in[14];
  const float* bih = (const float*)d_in[15];
  const float* bhh = (const float*)d_in[16];
  const float* linA_w = (const float*)d_in[17];
  const float* linA_b = (const float*)d_in[18];
  const float* linAf_w = (const float*)d_in[19];
  const float* linAf_b = (const float*)d_in[20];
  const float* linN_w = (const float*)d_in[21];
  const float* linN_b = (const float*)d_in[22];
  const float* linNf_w = (const float*)d_in[23];
  const float* linNf_b = (const float*)d_in[24];
  const float* fin_w = (const float*)d_in[25];
  const float* fin_b = (const float*)d_in[26];
  const float* finf_w = (const float*)d_in[27];
  const float* finf_b = (const float*)d_in[28];

  float* outA = (float*)d_out;
  float* outNodes = outA + BB * VAx;
  float* outF = outNodes + (size_t)NN * LL;

  char* basep = (char*)d_ws;
  size_t off = 0;
  auto alloc = [&](size_t bytes) -> void* {
    void* p = basep + off;
    off = (off + bytes + 255) & ~(size_t)255;
    return p;
  };

  unsigned int* x = (unsigned int*)alloc(sizeof(unsigned int) * NN * 64);   // bf16 pairs
  unsigned int* x2 = (unsigned int*)alloc(sizeof(unsigned int) * NN * 64);  // bf16 pairs
  float* hG = (float*)alloc(sizeof(float) * BB * HH);
  unsigned short* wcatT = (unsigned short*)alloc(sizeof(unsigned short) * HH * KC);
  unsigned short* linN2bt = (unsigned short*)alloc(sizeof(unsigned short) * HH * HH);
  unsigned short* Wihbt = (unsigned short*)alloc(sizeof(unsigned short) * 3 * HH * HH);
  unsigned short* linN1bt = (unsigned short*)alloc(sizeof(unsigned short) * HH * HH);
  float* WhhT = (float*)alloc(sizeof(float) * HH * 3 * HH);
  float* linAT = (float*)alloc(sizeof(float) * HH * HH);
  float* finT = (float*)alloc(sizeof(float) * HH * HH);
  float* part = (float*)alloc(sizeof(float) * BB * CHK * 25 * HH);
  unsigned short* ig = (unsigned short*)alloc(sizeof(unsigned short) * BB * LL * HH);
  float* gi = (float*)alloc(sizeof(float) * BB * LL * 3 * HH);
  float* part1 = (float*)alloc(sizeof(float) * BB * LL * HH);
  float* part2 = (float*)alloc(sizeof(float) * NN * HH);
  int* deg = (int*)alloc(sizeof(int) * NN * PS);
  int* cur = (int*)alloc(sizeof(int) * NN * PS);
  int* indptr = (int*)alloc(sizeof(int) * (NN + 1));
  int* esort = (int*)alloc(sizeof(int) * NE);
  int* bptr = (int*)alloc(sizeof(int) * (BB + 1));

  size_t remain = (ws_size > off) ? (ws_size - off) : 0;
  int NCk = NN;
  while ((size_t)NCk * KC * 2 > remain && NCk > 100) NCk >>= 1;
  unsigned int* A = (unsigned int*)alloc((size_t)NCk * (KC / 2) * sizeof(unsigned int));

  // ---- zero padded deg, then prep (weights/embed/count/boundary in one launch) ----
  hipMemsetAsync(deg, 0, sizeof(int) * NN * PS, stream);
  k_prep<<<(PREP_TOTAL + 255) / 256, 256, 0, stream>>>(
      rgcnW, rgcnRoot, wcatT, linN_w, linN2bt, Wih, Wihbt, Whh, WhhT, linA_w, linAT,
      fin_w, finT, linN1bt, nodeTypes, embN, x, deg, edst, bs, bptr);

  // ---- CSR: scan, scatter ----
  k_scane<<<1, 1024, 0, stream>>>(deg, indptr, cur);
  k_scattere<<<(NE + 255) / 256, 256, 0, stream>>>(esrc, edst, erel, cur, esort);

  // ---- 2 RGCN layers: agg (one wave/node) + 32-row-tile MFMA GEMM ----
  const unsigned int* xin = x;
  unsigned int* xout = x2;
  for (int layer = 0; layer < 2; ++layer) {
    for (int n0 = 0; n0 < NN; n0 += NCk) {
      int nc = NN - n0 < NCk ? NN - n0 : NCk;
      k_agg<<<(nc + 3) / 4, 256, 0, stream>>>(xin, indptr, esort, A, n0, nc);
      k_mgemm_rg32<<<nc / 32, 256, 0, stream>>>(
          (const unsigned short*)A, wcatT, rgcnB,
          (unsigned short*)xout + (size_t)n0 * HH);
    }
    const unsigned int* t = xin;
    xin = xout;
    xout = (unsigned int*)t;
  }
  const unsigned short* nodeEmb = (const unsigned short*)xin;

  // ---- aggS partial/reduce: produces ig (bf16, with SOS) and hG ----
  k_aggS_part<<<BB * CHK, 256, 0, stream>>>(seqin, nodeEmb, bptr, part);
  k_aggS_red<<<(BB * 25 * HH + 255) / 256, 256, 0, stream>>>(part, bptr, embA, actin, ig, hG);

  // ---- merged gi + part2 GEMMs + heads (one launch, 400 blocks) ----
  k_gp_heads<<<(BB * LL / 64) * 3 + NN / 64 + 2 * BB, 256, 0, stream>>>(
      ig, Wihbt, bih, gi, nodeEmb, linN2bt, part2, hG, linAT, linA_b, linAf_w, linAf_b,
      finT, fin_b, finf_w, finf_b, outA, outF);

  // ---- GRU recurrence + fused part1 ----
  k_gru<<<BB, 384, 0, stream>>>(gi, WhhT, bhh, hG, linN1bt, part1);

  // ---- fused logits + softmax ----
  k_logsm<<<BB * LL, 256, 0, stream>>>(part1, part2, linN_b, linNf_w, linNf_b, bptr,
                                       outNodes);
}

// Round 15
// 243.357 us; speedup vs baseline: 1.0715x; 1.0715x over previous
//
#include <hip/hip_runtime.h>
#include <math.h>

#define NN 12800
#define NE 204800
#define LL 24
#define HH 128
#define BB 64
#define RR 8
#define VAx 20
#define KC 1152  // R*H + H
#define CHK 8    // node chunks per batch for aggS
#define PS 16    // counter padding (ints per 64B line)

typedef __attribute__((ext_vector_type(8))) short bf16x8;
typedef __attribute__((ext_vector_type(4))) float f32x4;

__device__ inline unsigned short f2bf(float f) {
  unsigned u = __float_as_uint(f);
  unsigned r = u + 0x7FFF + ((u >> 16) & 1);  // RNE
  return (unsigned short)(r >> 16);
}
__device__ inline float bf2f(unsigned short s) {
  return __uint_as_float(((unsigned)s) << 16);
}
__device__ inline unsigned packbf(float lo, float hi) {
  return (unsigned)f2bf(lo) | ((unsigned)f2bf(hi) << 16);
}

// ---------------- mega prep: weight transforms + embed + edge count + batch boundary ----------------
// deg must be zeroed (hipMemsetAsync) BEFORE this kernel.
__global__ void k_prep(const float* __restrict__ rgcnW, const float* __restrict__ rgcnRoot,
                       unsigned short* __restrict__ wcatT,
                       const float* __restrict__ linN_w, unsigned short* __restrict__ linN2bt,
                       const float* __restrict__ Wih, unsigned short* __restrict__ Wihbt,
                       const float* __restrict__ Whh, float* __restrict__ WhhT,
                       const float* __restrict__ linA_w, float* __restrict__ linAT,
                       const float* __restrict__ fin_w, float* __restrict__ finT,
                       unsigned short* __restrict__ linN1bt,
                       const int* __restrict__ nt, const float* __restrict__ embN,
                       unsigned int* __restrict__ x, int* __restrict__ deg,
                       const int* __restrict__ edst, const int* __restrict__ bs,
                       int* __restrict__ bptr) {
  int idx = blockIdx.x * 256 + threadIdx.x;
  if (idx < HH * KC) {  // wcatT[d][k]
    int d = idx / KC, k = idx - d * KC;
    float v = (k < 1024) ? rgcnW[(k >> 7) * (HH * HH) + (k & 127) * HH + d]
                         : rgcnRoot[(k - 1024) * HH + d];
    wcatT[idx] = f2bf(v);
    return;
  }
  idx -= HH * KC;
  if (idx < HH * HH) {  // linN2bt[d][k] = linN_w[d][128+k]
    int d = idx >> 7, k = idx & 127;
    linN2bt[idx] = f2bf(linN_w[d * 2 * HH + HH + k]);
    return;
  }
  idx -= HH * HH;
  if (idx < 3 * HH * HH) {  // Wihbt = bf16(Wih), already [384][128] B-layout
    Wihbt[idx] = f2bf(Wih[idx]);
    return;
  }
  idx -= 3 * HH * HH;
  if (idx < 3 * HH * HH) {  // WhhT (fp32 transpose for GRU)
    int r = idx / HH, c = idx - r * HH;
    WhhT[c * 384 + r] = Whh[r * HH + c];
    return;
  }
  idx -= 3 * HH * HH;
  if (idx < HH * HH) {  // linAT
    int r = idx >> 7, c = idx & 127;
    linAT[c * HH + r] = linA_w[r * HH + c];
    return;
  }
  idx -= HH * HH;
  if (idx < HH * HH) {  // finT
    int r = idx >> 7, c = idx & 127;
    finT[c * HH + r] = fin_w[r * HH + c];
    return;
  }
  idx -= HH * HH;
  if (idx < HH * HH) {  // linN1bt[o][k] = bf16(linN_w[o][k])
    int o = idx >> 7, k = idx & 127;
    linN1bt[idx] = f2bf(linN_w[o * 2 * HH + k]);
    return;
  }
  idx -= HH * HH;
  if (idx < NN * 64) {  // embed -> bf16 pairs
    int n = idx >> 6, p = idx & 63;
    const float* e = embN + (size_t)nt[n] * HH + p * 2;
    x[idx] = packbf(e[0], e[1]);
    return;
  }
  idx -= NN * 64;
  if (idx < NE) {  // edge-degree count (padded counters, pre-zeroed)
    atomicAdd(&deg[edst[idx] * PS], 1);
    return;
  }
  idx -= NE;
  if (idx < NN) {  // bs sorted -> batch boundary detection
    int b = bs[idx];
    if (idx == 0 || bs[idx - 1] != b) bptr[b] = idx;
    if (idx == NN - 1) bptr[BB] = NN;
  }
}
#define PREP_TOTAL (HH * KC + HH * HH + 3 * HH * HH + 3 * HH * HH + HH * HH + HH * HH + HH * HH + NN * 64 + NE + NN)

// single-block scan over padded deg -> compact indptr + padded cur
__global__ __launch_bounds__(1024) void k_scane(const int* __restrict__ deg,
                                                int* __restrict__ indptr,
                                                int* __restrict__ cur) {
  __shared__ int ws[16];
  int tid = threadIdx.x;
  const int per = (NN + 1023) >> 10;
  int i0 = tid * per;
  int s = 0;
  for (int k = 0; k < per; ++k) {
    int i = i0 + k;
    if (i < NN) s += deg[i * PS];
  }
  int lane = tid & 63, wv = tid >> 6;
  int incl = s;
#pragma unroll
  for (int off = 1; off < 64; off <<= 1) {
    int t = __shfl_up(incl, off);
    if (lane >= off) incl += t;
  }
  if (lane == 63) ws[wv] = incl;
  __syncthreads();
  if (tid < 16) {
    int v = ws[tid];
    int inc = v;
#pragma unroll
    for (int off = 1; off < 16; off <<= 1) {
      int t = __shfl_up(inc, off);
      if (tid >= off) inc += t;
    }
    ws[tid] = inc - v;  // exclusive
  }
  __syncthreads();
  int run = ws[wv] + incl - s;
  for (int k = 0; k < per; ++k) {
    int i = i0 + k;
    if (i < NN) {
      indptr[i] = run;
      cur[i * PS] = run;
      run += deg[i * PS];
      if (i == NN - 1) indptr[NN] = run;
    }
  }
}

__global__ void k_scattere(const int* __restrict__ esrc, const int* __restrict__ edst,
                           const int* __restrict__ erel, int* __restrict__ cur,
                           int* __restrict__ esort) {
  int i = blockIdx.x * 256 + threadIdx.x;
  if (i >= NE) return;
  int p = atomicAdd(&cur[edst[i] * PS], 1);
  esort[p] = esrc[i] | (erel[i] << 16);
}

// ---------------- RGCN aggregation: one wave per node, 8-deep gather pipeline ----------------
__global__ __launch_bounds__(256) void k_agg(const unsigned int* __restrict__ x,
                                             const int* __restrict__ indptr,
                                             const int* __restrict__ esort,
                                             unsigned int* __restrict__ A, int n0, int nc) {
  int wid = ((blockIdx.x * 256) + threadIdx.x) >> 6;
  int lane = threadIdx.x & 63;
  if (wid >= nc) return;
  int n = n0 + wid;
  float a0=0,a1=0,a2=0,a3=0,a4=0,a5=0,a6=0,a7=0;
  float b0=0,b1=0,b2=0,b3=0,b4=0,b5=0,b6=0,b7=0;
  int c0=0,c1=0,c2=0,c3=0,c4=0,c5=0,c6=0,c7=0;
  int e0 = indptr[n], e1 = indptr[n + 1];

#define ACCV(RV, VV)                                                              \
  {                                                                               \
    float v0_ = bf2f((unsigned short)((VV) & 0xFFFF));                            \
    float v1_ = bf2f((unsigned short)((VV) >> 16));                               \
    switch (RV) {                                                                 \
      case 0: a0 += v0_; b0 += v1_; c0++; break;                                  \
      case 1: a1 += v0_; b1 += v1_; c1++; break;                                  \
      case 2: a2 += v0_; b2 += v1_; c2++; break;                                  \
      case 3: a3 += v0_; b3 += v1_; c3++; break;                                  \
      case 4: a4 += v0_; b4 += v1_; c4++; break;                                  \
      case 5: a5 += v0_; b5 += v1_; c5++; break;                                  \
      case 6: a6 += v0_; b6 += v1_; c6++; break;                                  \
      default: a7 += v0_; b7 += v1_; c7++; break;                                 \
    }                                                                             \
  }

  int e = e0;
  for (; e + 8 <= e1; e += 8) {  // 8 independent gather chains in flight
    int pk0 = esort[e + 0], pk1 = esort[e + 1], pk2 = esort[e + 2], pk3 = esort[e + 3];
    int pk4 = esort[e + 4], pk5 = esort[e + 5], pk6 = esort[e + 6], pk7 = esort[e + 7];
    unsigned v0 = x[(size_t)(pk0 & 0xFFFF) * 64 + lane];
    unsigned v1 = x[(size_t)(pk1 & 0xFFFF) * 64 + lane];
    unsigned v2 = x[(size_t)(pk2 & 0xFFFF) * 64 + lane];
    unsigned v3 = x[(size_t)(pk3 & 0xFFFF) * 64 + lane];
    unsigned v4 = x[(size_t)(pk4 & 0xFFFF) * 64 + lane];
    unsigned v5 = x[(size_t)(pk5 & 0xFFFF) * 64 + lane];
    unsigned v6 = x[(size_t)(pk6 & 0xFFFF) * 64 + lane];
    unsigned v7 = x[(size_t)(pk7 & 0xFFFF) * 64 + lane];
    ACCV(pk0 >> 16, v0);
    ACCV(pk1 >> 16, v1);
    ACCV(pk2 >> 16, v2);
    ACCV(pk3 >> 16, v3);
    ACCV(pk4 >> 16, v4);
    ACCV(pk5 >> 16, v5);
    ACCV(pk6 >> 16, v6);
    ACCV(pk7 >> 16, v7);
  }
  for (; e + 4 <= e1; e += 4) {
    int pk0 = esort[e + 0], pk1 = esort[e + 1], pk2 = esort[e + 2], pk3 = esort[e + 3];
    unsigned v0 = x[(size_t)(pk0 & 0xFFFF) * 64 + lane];
    unsigned v1 = x[(size_t)(pk1 & 0xFFFF) * 64 + lane];
    unsigned v2 = x[(size_t)(pk2 & 0xFFFF) * 64 + lane];
    unsigned v3 = x[(size_t)(pk3 & 0xFFFF) * 64 + lane];
    ACCV(pk0 >> 16, v0);
    ACCV(pk1 >> 16, v1);
    ACCV(pk2 >> 16, v2);
    ACCV(pk3 >> 16, v3);
  }
  for (; e < e1; ++e) {
    int pk = esort[e];
    unsigned v = x[(size_t)(pk & 0xFFFF) * 64 + lane];
    ACCV(pk >> 16, v);
  }
#undef ACCV

  unsigned int* Ar = A + (size_t)wid * (KC / 2);
  float i0 = 1.0f / (float)(c0 > 0 ? c0 : 1);
  float i1 = 1.0f / (float)(c1 > 0 ? c1 : 1);
  float i2 = 1.0f / (float)(c2 > 0 ? c2 : 1);
  float i3 = 1.0f / (float)(c3 > 0 ? c3 : 1);
  float i4 = 1.0f / (float)(c4 > 0 ? c4 : 1);
  float i5 = 1.0f / (float)(c5 > 0 ? c5 : 1);
  float i6 = 1.0f / (float)(c6 > 0 ? c6 : 1);
  float i7 = 1.0f / (float)(c7 > 0 ? c7 : 1);
  Ar[0 * 64 + lane] = packbf(a0 * i0, b0 * i0);
  Ar[1 * 64 + lane] = packbf(a1 * i1, b1 * i1);
  Ar[2 * 64 + lane] = packbf(a2 * i2, b2 * i2);
  Ar[3 * 64 + lane] = packbf(a3 * i3, b3 * i3);
  Ar[4 * 64 + lane] = packbf(a4 * i4, b4 * i4);
  Ar[5 * 64 + lane] = packbf(a5 * i5, b5 * i5);
  Ar[6 * 64 + lane] = packbf(a6 * i6, b6 * i6);
  Ar[7 * 64 + lane] = packbf(a7 * i7, b7 * i7);
  Ar[512 + lane] = x[n * 64 + lane];  // root term
}

// ---------------- RGCN GEMM, 32-row tiles: C=A*BT^T, bias+relu+bf16 ----------------
__global__ __launch_bounds__(256) void k_mgemm_rg32(const unsigned short* __restrict__ Abf,
                                                    const unsigned short* __restrict__ BTbf,
                                                    const float* __restrict__ bias,
                                                    unsigned short* __restrict__ C) {
  __shared__ unsigned int ldsu[(4096 + 16384) / 4];
  char* ldsc = (char*)ldsu;
  int tid = threadIdx.x;
  int m0 = blockIdx.x * 32;
  int w = tid >> 6, l = tid & 63;
  int lrow = l & 15, lg = l >> 4;
  int rowg = w & 1, colg = w >> 1;
  f32x4 acc[4] = {};

  const char* Ab = (const char*)Abf;
  const char* Bb = (const char*)BTbf;
  for (int kt = 0; kt < KC / 64; ++kt) {
    int k0 = kt << 6;
    {  // A: 32 rows x 64 cols bf16 = 4KB
      int slot = tid;
      int row = slot >> 3;
      int colb = (slot & 7) << 4;
      size_t srcb = ((size_t)(m0 + row) * KC + k0) * 2 + (size_t)(colb ^ ((row & 7) << 4));
      __builtin_amdgcn_global_load_lds((const unsigned int*)(Ab + srcb),
                                       (unsigned int*)(ldsc + slot * 16), 16, 0, 0);
    }
#pragma unroll
    for (int i = 0; i < 4; ++i) {  // B: 128 rows x 64 cols = 16KB at +4096
      int slot = i * 256 + tid;
      int row = slot >> 3;
      int colb = (slot & 7) << 4;
      size_t srcb = ((size_t)row * KC + k0) * 2 + (size_t)(colb ^ ((row & 7) << 4));
      __builtin_amdgcn_global_load_lds((const unsigned int*)(Bb + srcb),
                                       (unsigned int*)(ldsc + 4096 + slot * 16), 16, 0, 0);
    }
    __syncthreads();
#pragma unroll
    for (int h = 0; h < 2; ++h) {
      int arow = rowg * 16 + lrow;
      bf16x8 af = *(const bf16x8*)(ldsc + arow * 128 +
                                   ((h * 64 + lg * 16) ^ ((arow & 7) << 4)));
#pragma unroll
      for (int c = 0; c < 4; ++c) {
        int brow = (colg * 4 + c) * 16 + lrow;
        bf16x8 bfr = *(const bf16x8*)(ldsc + 4096 + brow * 128 +
                                      ((h * 64 + lg * 16) ^ ((brow & 7) << 4)));
        acc[c] = __builtin_amdgcn_mfma_f32_16x16x32_bf16(af, bfr, acc[c], 0, 0, 0);
      }
    }
    __syncthreads();
  }
#pragma unroll
  for (int c = 0; c < 4; ++c) {
    int gn = (colg * 4 + c) * 16 + lrow;
    float bv = bias[gn];
#pragma unroll
    for (int r = 0; r < 4; ++r) {
      int gm = m0 + rowg * 16 + lg * 4 + r;
      float v = fmaxf(acc[c][r] + bv, 0.f);
      C[(size_t)gm * HH + gn] = f2bf(v);
    }
  }
}

// ---------------- bf16 MFMA GEMM template (verified KT-loop staging) ----------------
template <int OUTMODE>
__global__ __launch_bounds__(256) void k_mgemm(const unsigned short* __restrict__ Abf, int lda,
                                               const unsigned short* __restrict__ BTbf, int ldb,
                                               const float* __restrict__ bias,
                                               void* __restrict__ C, int ldc, int M, int K) {
  __shared__ unsigned int ldsu[(8192 + 16384) / 4];
  char* ldsc = (char*)ldsu;
  int tid = threadIdx.x;
  int m0 = blockIdx.x * 64;
  int n0c = blockIdx.y * 128;
  int w = tid >> 6, l = tid & 63;
  int lrow = l & 15, lg = l >> 4;
  f32x4 acc[8] = {};

  const char* Ab = (const char*)Abf;
  const char* Bb = (const char*)(BTbf + (size_t)n0c * ldb);
  int KT = K >> 6;
  for (int kt = 0; kt < KT; ++kt) {
    int k0 = kt << 6;
#pragma unroll
    for (int i = 0; i < 2; ++i) {
      int slot = i * 256 + tid;
      int row = slot >> 3;
      int colb = (slot & 7) << 4;
      int gr = m0 + row;
      gr = gr < M ? gr : M - 1;
      size_t srcb = ((size_t)gr * lda + k0) * 2 + (size_t)(colb ^ ((row & 7) << 4));
      __builtin_amdgcn_global_load_lds((const unsigned int*)(Ab + srcb),
                                       (unsigned int*)(ldsc + slot * 16), 16, 0, 0);
    }
#pragma unroll
    for (int i = 0; i < 4; ++i) {
      int slot = i * 256 + tid;
      int row = slot >> 3;
      int colb = (slot & 7) << 4;
      size_t srcb = ((size_t)row * ldb + k0) * 2 + (size_t)(colb ^ ((row & 7) << 4));
      __builtin_amdgcn_global_load_lds((const unsigned int*)(Bb + srcb),
                                       (unsigned int*)(ldsc + 8192 + slot * 16), 16, 0, 0);
    }
    __syncthreads();
#pragma unroll
    for (int h = 0; h < 2; ++h) {
      int arow = w * 16 + lrow;
      bf16x8 af = *(const bf16x8*)(ldsc + arow * 128 +
                                   ((h * 64 + lg * 16) ^ ((arow & 7) << 4)));
#pragma unroll
      for (int c = 0; c < 8; ++c) {
        int brow = c * 16 + lrow;
        bf16x8 bf = *(const bf16x8*)(ldsc + 8192 + brow * 128 +
                                     ((h * 64 + lg * 16) ^ ((brow & 7) << 4)));
        acc[c] = __builtin_amdgcn_mfma_f32_16x16x32_bf16(af, bf, acc[c], 0, 0, 0);
      }
    }
    __syncthreads();
  }
#pragma unroll
  for (int c = 0; c < 8; ++c) {
#pragma unroll
    for (int r = 0; r < 4; ++r) {
      int gm = m0 + w * 16 + lg * 4 + r;
      if (gm >= M) continue;
      int gn = n0c + c * 16 + lrow;
      float v = acc[c][r];
      if (OUTMODE == 1) {
        v = fmaxf(v + bias[gn], 0.f);
        ((unsigned short*)C)[(size_t)gm * ldc + gn] = f2bf(v);
      } else if (OUTMODE == 2) {
        ((float*)C)[(size_t)gm * ldc + gn] = v + bias[gn];
      } else {
        ((float*)C)[(size_t)gm * ldc + gn] = v;
      }
    }
  }
}

// ---------------- merged gi + part2 GEMMs + heads (all depend only on aggS_red) ----------------
// blocks [0,72): gi = ig @ Wih^T + bih (N split 3x128). [72,272): part2. [272,400): heads.
__global__ __launch_bounds__(256) void k_gp_heads(const unsigned short* __restrict__ ig,
                                                  const unsigned short* __restrict__ Wihbt,
                                                  const float* __restrict__ bih,
                                                  float* __restrict__ gi,
                                                  const unsigned short* __restrict__ nodeEmb,
                                                  const unsigned short* __restrict__ linN2bt,
                                                  float* __restrict__ part2,
                                                  const float* __restrict__ hG,
                                                  const float* __restrict__ linAT,
                                                  const float* __restrict__ linA_b,
                                                  const float* __restrict__ linAf_w,
                                                  const float* __restrict__ linAf_b,
                                                  const float* __restrict__ finT,
                                                  const float* __restrict__ fin_b,
                                                  const float* __restrict__ finf_w,
                                                  const float* __restrict__ finf_b,
                                                  float* __restrict__ outA,
                                                  float* __restrict__ outF) {
  int tid = threadIdx.x;
  int bid = blockIdx.x;
  const int GIB = (BB * LL / 64) * 3;      // 72
  const int GEMMB = GIB + NN / 64;         // 272
  if (bid >= GEMMB) {  // ---- heads ----
    int hb = bid - GEMMB;
    int b = hb >> 1, which = hb & 1, j = tid;
    __shared__ float hsh[HH], t1[HH];
    if (j < HH) hsh[j] = hG[b * HH + j];
    __syncthreads();
    if (j < HH) {
      const float* Wt = which ? finT : linAT;
      const float* bb = which ? fin_b : linA_b;
      float s = bb[j];
      for (int k = 0; k < HH; ++k) s = fmaf(hsh[k], Wt[k * HH + j], s);
      t1[j] = fmaxf(s, 0.f);
    }
    __syncthreads();
    if (which == 0) {
      if (j < VAx) {
        float o = linAf_b[j];
        for (int k = 0; k < HH; ++k) o = fmaf(t1[k], linAf_w[j * HH + k], o);
        outA[b * VAx + j] = o;
      }
    } else if (j == 0) {
      float o = finf_b[0];
      for (int k = 0; k < HH; ++k) o = fmaf(t1[k], finf_w[k], o);
      outF[b] = 1.f / (1.f + expf(-o));
    }
    return;
  }
  // ---- GEMMs ----
  __shared__ unsigned int ldsu[(8192 + 16384) / 4];
  char* ldsc = (char*)ldsu;
  const unsigned short* Abf;
  const unsigned short* BTbf;
  const float* bias;
  float* Cf;
  int m0, ldc, withbias;
  if (bid < GIB) {
    int mb = bid / 3, nc = bid % 3;
    Abf = ig;
    BTbf = Wihbt + (size_t)(nc * 128) * HH;
    bias = bih + nc * 128;
    Cf = gi + nc * 128;
    m0 = mb * 64;
    ldc = 3 * HH;
    withbias = 1;
  } else {
    Abf = nodeEmb;
    BTbf = linN2bt;
    bias = nullptr;
    Cf = part2;
    m0 = (bid - GIB) * 64;
    ldc = HH;
    withbias = 0;
  }
  int w = tid >> 6, l = tid & 63;
  int lrow = l & 15, lg = l >> 4;
  f32x4 acc[8] = {};
  const char* Ab = (const char*)Abf;
  const char* Bb = (const char*)BTbf;
  for (int kt = 0; kt < 2; ++kt) {  // K = 128
    int k0 = kt << 6;
#pragma unroll
    for (int i = 0; i < 2; ++i) {
      int slot = i * 256 + tid;
      int row = slot >> 3;
      int colb = (slot & 7) << 4;
      size_t srcb = ((size_t)(m0 + row) * HH + k0) * 2 + (size_t)(colb ^ ((row & 7) << 4));
      __builtin_amdgcn_global_load_lds((const unsigned int*)(Ab + srcb),
                                       (unsigned int*)(ldsc + slot * 16), 16, 0, 0);
    }
#pragma unroll
    for (int i = 0; i < 4; ++i) {
      int slot = i * 256 + tid;
      int row = slot >> 3;
      int colb = (slot & 7) << 4;
      size_t srcb = ((size_t)row * HH + k0) * 2 + (size_t)(colb ^ ((row & 7) << 4));
      __builtin_amdgcn_global_load_lds((const unsigned int*)(Bb + srcb),
                                       (unsigned int*)(ldsc + 8192 + slot * 16), 16, 0, 0);
    }
    __syncthreads();
#pragma unroll
    for (int h = 0; h < 2; ++h) {
      int arow = w * 16 + lrow;
      bf16x8 af = *(const bf16x8*)(ldsc + arow * 128 +
                                   ((h * 64 + lg * 16) ^ ((arow & 7) << 4)));
#pragma unroll
      for (int c = 0; c < 8; ++c) {
        int brow = c * 16 + lrow;
        bf16x8 bfr = *(const bf16x8*)(ldsc + 8192 + brow * 128 +
                                      ((h * 64 + lg * 16) ^ ((brow & 7) << 4)));
        acc[c] = __builtin_amdgcn_mfma_f32_16x16x32_bf16(af, bfr, acc[c], 0, 0, 0);
      }
    }
    __syncthreads();
  }
#pragma unroll
  for (int c = 0; c < 8; ++c) {
    int gn = c * 16 + lrow;
    float bv = withbias ? bias[gn] : 0.f;
#pragma unroll
    for (int r = 0; r < 4; ++r) {
      int gm = m0 + w * 16 + lg * 4 + r;
      Cf[(size_t)gm * ldc + gn] = acc[c][r] + bv;
    }
  }
}

// ---------------- aggS partials: 512 blocks (64 batches x 8 chunks) ----------------
__global__ __launch_bounds__(256) void k_aggS_part(const float* __restrict__ seqin,
                                                   const unsigned short* __restrict__ x,
                                                   const int* __restrict__ bptr,
                                                   float* __restrict__ part) {
  int bc = blockIdx.x, b = bc >> 3, c = bc & 7;
  int h = threadIdx.x & 127, l0 = threadIdx.x >> 7;  // l0 in {0,1}
  int i0 = bptr[b], i1 = bptr[b + 1];
  int len = i1 - i0;
  int per = (len + CHK - 1) / CHK;
  int j0 = i0 + c * per;
  int j1 = j0 + per;
  if (j1 > i1) j1 = i1;
  float acc[12] = {};
  float esum = 0.f;
  for (int n = j0; n < j1; ++n) {  // bnodes == identity (bs sorted)
    float e = bf2f(x[n * HH + h]);
    esum += e;
    const float* srow = seqin + (size_t)n * LL;
#pragma unroll
    for (int t = 0; t < 12; ++t) acc[t] = fmaf(srow[l0 + 2 * t], e, acc[t]);
  }
  float* p = part + (size_t)bc * 25 * HH + h;
#pragma unroll
  for (int t = 0; t < 12; ++t) p[(l0 + 2 * t) * HH] = acc[t];
  if (l0 == 0) p[24 * HH] = esum;
}

// reduce partials; writes ig (bf16, with SOS at t=0) and hG (fp32)
__global__ void k_aggS_red(const float* __restrict__ part, const int* __restrict__ bptr,
                           const float* __restrict__ embA, const int* __restrict__ act,
                           unsigned short* __restrict__ ig, float* __restrict__ hG) {
  int idx = blockIdx.x * 256 + threadIdx.x;
  if (idx >= BB * 25 * HH) return;
  int h = idx & 127;
  int rem = idx >> 7;
  int l = rem % 25, b = rem / 25;
  if (l == 23) {  // agg[23] dropped by [:, :L]; reuse slot for ig[b][0] = SOS
    ig[((size_t)b * LL) * HH + h] = f2bf(embA[(size_t)act[b] * HH + h]);
    return;
  }
  float s = 0.f;
#pragma unroll
  for (int c = 0; c < CHK; ++c) s += part[(((size_t)(b * CHK + c)) * 25 + l) * HH + h];
  if (l == 24) {
    int len = bptr[b + 1] - bptr[b];
    hG[b * HH + h] = s / (float)len;
  } else {
    ig[((size_t)b * LL + l + 1) * HH + h] = f2bf(s);
  }
}

// ---------------- GRU: 64 blocks x 384 threads, Whh column in registers ----------------
__global__ __launch_bounds__(384) void k_gru(const float* __restrict__ gi,
                                             const float* __restrict__ WhhT,  // [128][384]
                                             const float* __restrict__ bhh,
                                             const float* __restrict__ hG,
                                             unsigned short* __restrict__ seqout) {
  int b = blockIdx.x, tid = threadIdx.x;
  int gate = tid >> 7, j = tid & 127;
  __shared__ float h[HH];
  __shared__ float sz[HH], sg[HH];
  float w[HH];
#pragma unroll
  for (int k = 0; k < HH; ++k) w[k] = WhhT[k * 384 + tid];
  float bh = bhh[tid];
  if (tid < HH) h[tid] = hG[b * HH + tid];
  __syncthreads();
  const float* gib = gi + (size_t)b * LL * 384;
  for (int t = 0; t < LL; ++t) {
    float giv = gib[t * 384 + tid];
    float gin = (gate == 0) ? gib[t * 384 + 256 + j] : 0.f;  // wave-uniform branch
    float hj = h[j];
    float g0 = 0.f, g1 = 0.f, g2 = 0.f, g3 = 0.f;
    const float4* h4 = (const float4*)h;
#pragma unroll
    for (int k4 = 0; k4 < HH / 4; ++k4) {
      float4 hv = h4[k4];
      g0 = fmaf(w[4 * k4 + 0], hv.x, g0);
      g1 = fmaf(w[4 * k4 + 1], hv.y, g1);
      g2 = fmaf(w[4 * k4 + 2], hv.z, g2);
      g3 = fmaf(w[4 * k4 + 3], hv.w, g3);
    }
    float g = bh + ((g0 + g1) + (g2 + g3));
    float r = 0.f;
    if (gate == 0) {
      r = 1.f / (1.f + expf(-(giv + g)));
    } else if (gate == 1) {
      sz[j] = 1.f / (1.f + expf(-(giv + g)));
    } else {
      sg[j] = g;
    }
    __syncthreads();
    if (gate == 0) {
      float n = tanhf(gin + r * sg[j]);
      float z = sz[j];
      float hn = (1.f - z) * n + z * hj;
      h[j] = hn;
      seqout[((size_t)b * LL + t) * HH + j] = f2bf(hn);
    }
    __syncthreads();
  }
}

// ---------------- fused logits + segment softmax: one block per (b,l) ----------------
__global__ __launch_bounds__(256) void k_logsm(const float* __restrict__ part1,
                                               const float* __restrict__ part2,
                                               const float* __restrict__ linN_b,
                                               const float* __restrict__ linNf_w,
                                               const float* __restrict__ linNf_b,
                                               const int* __restrict__ bptr,
                                               float* __restrict__ outN) {
  int bl = blockIdx.x;
  int b = bl / LL, l = bl % LL;
  __shared__ float p1b[HH], wsh[HH], lg[256], red[8];
  int tid = threadIdx.x;
  int w = tid >> 6, lane = tid & 63;
  if (tid < HH) {
    p1b[tid] = part1[((size_t)b * LL + l) * HH + tid] + linN_b[tid];
    wsh[tid] = linNf_w[tid];
  }
  __syncthreads();
  int i0 = bptr[b], i1 = bptr[b + 1];
  int len = i1 - i0;  // 200 for this problem (<=256 assumed)
  float bf = linNf_b[0];
  for (int i = i0 + w; i < i1; i += 4) {
    const float* p2 = part2 + (size_t)i * HH;
    float v = fmaxf(p1b[lane] + p2[lane], 0.f) * wsh[lane] +
              fmaxf(p1b[64 + lane] + p2[64 + lane], 0.f) * wsh[64 + lane];
#pragma unroll
    for (int off = 32; off > 0; off >>= 1) v += __shfl_down(v, off);
    if (lane == 0) lg[i - i0] = v + bf;
  }
  __syncthreads();
  float m = (tid < len) ? lg[tid] : -1e30f;
#pragma unroll
  for (int off = 32; off > 0; off >>= 1) m = fmaxf(m, __shfl_xor(m, off));
  if (lane == 0) red[w] = m;
  __syncthreads();
  m = fmaxf(fmaxf(red[0], red[1]), fmaxf(red[2], red[3]));
  float e = (tid < len) ? expf(lg[tid] - m) : 0.f;
  float s = e;
#pragma unroll
  for (int off = 32; off > 0; off >>= 1) s += __shfl_xor(s, off);
  if (lane == 0) red[4 + w] = s;
  __syncthreads();
  s = (red[4] + red[5]) + (red[6] + red[7]);
  if (tid < len) outN[(size_t)(i0 + tid) * LL + l] = e / s;
}

// ---------------- host ----------------
extern "C" void kernel_launch(void* const* d_in, const int* in_sizes, int n_in,
                              void* d_out, int out_size, void* d_ws, size_t ws_size,
                              hipStream_t stream) {
  const int* nodeTypes = (const int*)d_in[0];
  const int* esrc = (const int*)d_in[1];
  const int* edst = esrc + NE;
  const int* erel = (const int*)d_in[2];
  const int* bs = (const int*)d_in[3];
  const float* seqin = (const float*)d_in[4];
  const int* actin = (const int*)d_in[7];
  const float* embN = (const float*)d_in[8];
  const float* embA = (const float*)d_in[9];
  const float* rgcnW = (const float*)d_in[10];
  const float* rgcnRoot = (const float*)d_in[11];
  const float* rgcnB = (const float*)d_in[12];
  const float* Wih = (const float*)d_in[13];
  const float* Whh = (const float*)d_in[14];
  const float* bih = (const float*)d_in[15];
  const float* bhh = (const float*)d_in[16];
  const float* linA_w = (const float*)d_in[17];
  const float* linA_b = (const float*)d_in[18];
  const float* linAf_w = (const float*)d_in[19];
  const float* linAf_b = (const float*)d_in[20];
  const float* linN_w = (const float*)d_in[21];
  const float* linN_b = (const float*)d_in[22];
  const float* linNf_w = (const float*)d_in[23];
  const float* linNf_b = (const float*)d_in[24];
  const float* fin_w = (const float*)d_in[25];
  const float* fin_b = (const float*)d_in[26];
  const float* finf_w = (const float*)d_in[27];
  const float* finf_b = (const float*)d_in[28];

  float* outA = (float*)d_out;
  float* outNodes = outA + BB * VAx;
  float* outF = outNodes + (size_t)NN * LL;

  char* basep = (char*)d_ws;
  size_t off = 0;
  auto alloc = [&](size_t bytes) -> void* {
    void* p = basep + off;
    off = (off + bytes + 255) & ~(size_t)255;
    return p;
  };

  unsigned int* x = (unsigned int*)alloc(sizeof(unsigned int) * NN * 64);   // bf16 pairs
  unsigned int* x2 = (unsigned int*)alloc(sizeof(unsigned int) * NN * 64);  // bf16 pairs
  float* hG = (float*)alloc(sizeof(float) * BB * HH);
  unsigned short* wcatT = (unsigned short*)alloc(sizeof(unsigned short) * HH * KC);
  unsigned short* linN2bt = (unsigned short*)alloc(sizeof(unsigned short) * HH * HH);
  unsigned short* Wihbt = (unsigned short*)alloc(sizeof(unsigned short) * 3 * HH * HH);
  unsigned short* linN1bt = (unsigned short*)alloc(sizeof(unsigned short) * HH * HH);
  float* WhhT = (float*)alloc(sizeof(float) * HH * 3 * HH);
  float* linAT = (float*)alloc(sizeof(float) * HH * HH);
  float* finT = (float*)alloc(sizeof(float) * HH * HH);
  float* part = (float*)alloc(sizeof(float) * BB * CHK * 25 * HH);
  unsigned short* ig = (unsigned short*)alloc(sizeof(unsigned short) * BB * LL * HH);
  float* gi = (float*)alloc(sizeof(float) * BB * LL * 3 * HH);
  unsigned short* seqb = (unsigned short*)alloc(sizeof(unsigned short) * BB * LL * HH);
  float* part1 = (float*)alloc(sizeof(float) * BB * LL * HH);
  float* part2 = (float*)alloc(sizeof(float) * NN * HH);
  int* deg = (int*)alloc(sizeof(int) * NN * PS);
  int* cur = (int*)alloc(sizeof(int) * NN * PS);
  int* indptr = (int*)alloc(sizeof(int) * (NN + 1));
  int* esort = (int*)alloc(sizeof(int) * NE);
  int* bptr = (int*)alloc(sizeof(int) * (BB + 1));

  size_t remain = (ws_size > off) ? (ws_size - off) : 0;
  int NCk = NN;
  while ((size_t)NCk * KC * 2 > remain && NCk > 100) NCk >>= 1;
  unsigned int* A = (unsigned int*)alloc((size_t)NCk * (KC / 2) * sizeof(unsigned int));

  // ---- zero padded deg, then prep (weights/embed/count/boundary in one launch) ----
  hipMemsetAsync(deg, 0, sizeof(int) * NN * PS, stream);
  k_prep<<<(PREP_TOTAL + 255) / 256, 256, 0, stream>>>(
      rgcnW, rgcnRoot, wcatT, linN_w, linN2bt, Wih, Wihbt, Whh, WhhT, linA_w, linAT,
      fin_w, finT, linN1bt, nodeTypes, embN, x, deg, edst, bs, bptr);

  // ---- CSR: scan, scatter ----
  k_scane<<<1, 1024, 0, stream>>>(deg, indptr, cur);
  k_scattere<<<(NE + 255) / 256, 256, 0, stream>>>(esrc, edst, erel, cur, esort);

  // ---- 2 RGCN layers: agg (one wave/node) + 32-row-tile MFMA GEMM ----
  const unsigned int* xin = x;
  unsigned int* xout = x2;
  for (int layer = 0; layer < 2; ++layer) {
    for (int n0 = 0; n0 < NN; n0 += NCk) {
      int nc = NN - n0 < NCk ? NN - n0 : NCk;
      k_agg<<<(nc + 3) / 4, 256, 0, stream>>>(xin, indptr, esort, A, n0, nc);
      k_mgemm_rg32<<<nc / 32, 256, 0, stream>>>(
          (const unsigned short*)A, wcatT, rgcnB,
          (unsigned short*)xout + (size_t)n0 * HH);
    }
    const unsigned int* t = xin;
    xin = xout;
    xout = (unsigned int*)t;
  }
  const unsigned short* nodeEmb = (const unsigned short*)xin;

  // ---- aggS partial/reduce: produces ig (bf16, with SOS) and hG ----
  k_aggS_part<<<BB * CHK, 256, 0, stream>>>(seqin, nodeEmb, bptr, part);
  k_aggS_red<<<(BB * 25 * HH + 255) / 256, 256, 0, stream>>>(part, bptr, embA, actin, ig, hG);

  // ---- merged gi + part2 GEMMs + heads (one launch, 400 blocks) ----
  k_gp_heads<<<(BB * LL / 64) * 3 + NN / 64 + 2 * BB, 256, 0, stream>>>(
      ig, Wihbt, bih, gi, nodeEmb, linN2bt, part2, hG, linAT, linA_b, linAf_w, linAf_b,
      finT, fin_b, finf_w, finf_b, outA, outF);

  // ---- GRU recurrence ----
  k_gru<<<BB, 384, 0, stream>>>(gi, WhhT, bhh, hG, seqb);

  // ---- part1 = seqb @ linN1^T ----
  {
    dim3 g((BB * LL) / 64, 1);
    k_mgemm<0><<<g, 256, 0, stream>>>(seqb, HH, linN1bt, HH, nullptr, (void*)part1, HH,
                                      BB * LL, HH);
  }
  // ---- fused logits + softmax ----
  k_logsm<<<BB * LL, 256, 0, stream>>>(part1, part2, linN_b, linNf_w, linNf_b, bptr,
                                       outNodes);
}